// Round 1
// baseline (764.054 us; speedup 1.0000x reference)
//
#include <hip/hip_runtime.h>

#define DIM 768
#define HEADS 12
#define HD 64
#define BB 8
#define NN 512
#define BN (BB*NN)                 // 4096
#define QKV_COLS (3*DIM)           // 2304
#define OUT0_ELEMS ((size_t)BB*NN*DIM)          // 3145728
#define BHND ((size_t)BB*HEADS*NN*HD)           // 3145728

// ---------------- Kernel 1: QKV GEMM + scatter to (B,H,N,64) ----------------
__global__ __launch_bounds__(256) void qkv_kernel(
    const float* __restrict__ x, const float* __restrict__ w,
    float* __restrict__ qws, float* __restrict__ kws, float* __restrict__ vws)
{
  __shared__ float As[32][65];
  __shared__ float Bs[32][65];
  const int bx = blockIdx.x;      // 0..35 col tile (64 cols of 2304)
  const int by = blockIdx.y;      // 0..63 row tile (64 rows of 4096)
  const int t = threadIdx.x;
  const int ty = t >> 4, tx = t & 15;
  const float* A = x + (size_t)by * 64 * DIM;
  const float* Bw = w + (size_t)bx * 64 * DIM;
  float acc[4][4] = {};
  for (int kc = 0; kc < DIM; kc += 32) {
    #pragma unroll
    for (int i = 0; i < 2; ++i) {
      int f = t + 256 * i;
      int row = f >> 3, k4 = (f & 7) << 2;
      float4 av = *(const float4*)(A + (size_t)row * DIM + kc + k4);
      float4 bv = *(const float4*)(Bw + (size_t)row * DIM + kc + k4);
      As[k4+0][row]=av.x; As[k4+1][row]=av.y; As[k4+2][row]=av.z; As[k4+3][row]=av.w;
      Bs[k4+0][row]=bv.x; Bs[k4+1][row]=bv.y; Bs[k4+2][row]=bv.z; Bs[k4+3][row]=bv.w;
    }
    __syncthreads();
    #pragma unroll
    for (int kk = 0; kk < 32; ++kk) {
      float a[4], bb[4];
      #pragma unroll
      for (int i=0;i<4;++i) a[i]=As[kk][ty*4+i];
      #pragma unroll
      for (int j=0;j<4;++j) bb[j]=Bs[kk][tx*4+j];
      #pragma unroll
      for (int i=0;i<4;++i)
        #pragma unroll
        for (int j=0;j<4;++j) acc[i][j] += a[i]*bb[j];
    }
    __syncthreads();
  }
  const int colBase = bx * 64;
  const int sel = colBase / DIM;            // 0=q 1=k 2=v (tiles never straddle)
  const int h = (colBase % DIM) / HD;       // uniform per tile
  float* dst = sel == 0 ? qws : (sel == 1 ? kws : vws);
  #pragma unroll
  for (int i = 0; i < 4; ++i) {
    int gm = by*64 + ty*4 + i;
    int b = gm >> 9, n = gm & 511;
    float* p = dst + (((size_t)(b*HEADS + h)*NN + n) << 6) + tx*4;
    *(float4*)p = make_float4(acc[i][0], acc[i][1], acc[i][2], acc[i][3]);
  }
}

// ---------------- Kernel 2: per-row L2-normalize + square (in place) ----------------
// q2_d = q_d^2 / sum_d q_d^2  (one 64-lane wave per (b,h,n) row)
__global__ __launch_bounds__(256) void normsq_kernel(float* __restrict__ q, float* __restrict__ k)
{
  const int wave = (blockIdx.x * 256 + threadIdx.x) >> 6;   // row id, 0..49151
  const int lane = threadIdx.x & 63;
  const size_t idx = ((size_t)wave << 6) + lane;
  float qv = q[idx], kv = k[idx];
  float qs = qv*qv, ks = kv*kv;
  #pragma unroll
  for (int off = 32; off; off >>= 1) {
    qs += __shfl_xor(qs, off);
    ks += __shfl_xor(ks, off);
  }
  q[idx] = qv*qv / qs;
  k[idx] = kv*kv / ks;
}

// ---------------- Kernel 3: attn = q2 @ k2^T (per b,h), raw -> d_out attn, + LN stats ----------------
__global__ __launch_bounds__(256) void attn_kernel(
    const float* __restrict__ q2, const float* __restrict__ k2,
    float* __restrict__ attn_out, double* __restrict__ hsum)
{
  __shared__ float As[64][65];
  __shared__ float Bs[64][65];
  __shared__ float red[8];
  const int tile = blockIdx.x;           // 0..63
  const int h = blockIdx.y, b = blockIdx.z;
  const int rowBase = (tile >> 3) * 64;  // n
  const int colBase = (tile & 7) * 64;   // m
  const float* A  = q2 + (((size_t)(b*HEADS + h)*NN + rowBase) << 6);
  const float* Bm = k2 + (((size_t)(b*HEADS + h)*NN + colBase) << 6);
  const int t = threadIdx.x;
  const int ty = t >> 4, tx = t & 15;
  #pragma unroll
  for (int i = 0; i < 4; ++i) {
    int f = t + 256*i;
    int row = f >> 4, k4 = (f & 15) << 2;
    float4 av = *(const float4*)(A  + ((size_t)row << 6) + k4);
    float4 bv = *(const float4*)(Bm + ((size_t)row << 6) + k4);
    As[k4+0][row]=av.x; As[k4+1][row]=av.y; As[k4+2][row]=av.z; As[k4+3][row]=av.w;
    Bs[k4+0][row]=bv.x; Bs[k4+1][row]=bv.y; Bs[k4+2][row]=bv.z; Bs[k4+3][row]=bv.w;
  }
  __syncthreads();
  float acc[4][4] = {};
  #pragma unroll
  for (int kk = 0; kk < 64; ++kk) {
    float a[4], bb[4];
    #pragma unroll
    for (int i=0;i<4;++i) a[i]=As[kk][ty*4+i];
    #pragma unroll
    for (int j=0;j<4;++j) bb[j]=Bs[kk][tx*4+j];
    #pragma unroll
    for (int i=0;i<4;++i)
      #pragma unroll
      for (int j=0;j<4;++j) acc[i][j] += a[i]*bb[j];
  }
  float* out = attn_out + ((size_t)(b*HEADS + h)*NN + rowBase)*NN + colBase;
  float s1 = 0.f, s2 = 0.f;
  #pragma unroll
  for (int i = 0; i < 4; ++i) {
    #pragma unroll
    for (int j = 0; j < 4; ++j) { s1 += acc[i][j]; s2 += acc[i][j]*acc[i][j]; }
    *(float4*)(out + (size_t)(ty*4+i)*NN + tx*4) =
        make_float4(acc[i][0], acc[i][1], acc[i][2], acc[i][3]);
  }
  // block-reduce stats -> double atomics
  #pragma unroll
  for (int off = 32; off; off >>= 1) { s1 += __shfl_xor(s1, off); s2 += __shfl_xor(s2, off); }
  if ((t & 63) == 0) { red[t >> 6] = s1; red[4 + (t >> 6)] = s2; }
  __syncthreads();
  if (t == 0) {
    double d1 = (double)red[0] + red[1] + red[2] + red[3];
    double d2 = (double)red[4] + red[5] + red[6] + red[7];
    atomicAdd(&hsum[b*2],   d1);
    atomicAdd(&hsum[b*2+1], d2);
  }
}

// ---------------- Kernel 4: LN (in place on d_out attn) + out_bh = attn @ v ----------------
__global__ __launch_bounds__(256) void norm_pv_kernel(
    float* __restrict__ attn, const float* __restrict__ vws,
    const float* __restrict__ lnw, const float* __restrict__ lnb,
    const double* __restrict__ hsum, float* __restrict__ obh)
{
  __shared__ float As[64][65];
  __shared__ float Bs[64][65];
  const int rt = blockIdx.x;   // 0..7 row tile
  const int h = blockIdx.y, b = blockIdx.z;
  const int rowBase = rt * 64;
  const double cnt = (double)HEADS * NN * NN;
  const double s1 = hsum[b*2], s2 = hsum[b*2+1];
  const double mu = s1 / cnt;
  const double var = s2 / cnt - mu * mu;
  const float mean = (float)mu;
  const float istd = (float)(1.0 / sqrt(var + 1e-5));
  float* arow = attn + ((size_t)(b*HEADS + h)*NN + rowBase)*NN;
  const float* lwrow = lnw + ((size_t)h*NN + rowBase)*NN;
  const float* lbrow = lnb + ((size_t)h*NN + rowBase)*NN;
  const float* V = vws + (((size_t)(b*HEADS + h)*NN) << 6);
  const int t = threadIdx.x;
  const int ty = t >> 4, tx = t & 15;
  float acc[4][4] = {};
  for (int kc = 0; kc < NN; kc += 64) {
    #pragma unroll
    for (int i = 0; i < 4; ++i) {
      int f = t + 256*i;
      int row = f >> 4, c4 = (f & 15) << 2;
      size_t g = (size_t)row*NN + kc + c4;
      float4 rv = *(const float4*)(arow + g);
      float4 lw = *(const float4*)(lwrow + g);
      float4 lb = *(const float4*)(lbrow + g);
      float4 nv;
      nv.x = (rv.x - mean)*istd*lw.x + lb.x;
      nv.y = (rv.y - mean)*istd*lw.y + lb.y;
      nv.z = (rv.z - mean)*istd*lw.z + lb.z;
      nv.w = (rv.w - mean)*istd*lw.w + lb.w;
      *(float4*)(arow + g) = nv;                 // final attn output (in place)
      As[c4+0][row]=nv.x; As[c4+1][row]=nv.y; As[c4+2][row]=nv.z; As[c4+3][row]=nv.w;
      float4 vv = *(const float4*)(V + ((size_t)(kc + row) << 6) + c4);
      Bs[row][c4+0]=vv.x; Bs[row][c4+1]=vv.y; Bs[row][c4+2]=vv.z; Bs[row][c4+3]=vv.w;
    }
    __syncthreads();
    #pragma unroll
    for (int kk = 0; kk < 64; ++kk) {
      float a[4], bb[4];
      #pragma unroll
      for (int i=0;i<4;++i) a[i]=As[kk][ty*4+i];
      #pragma unroll
      for (int j=0;j<4;++j) bb[j]=Bs[kk][tx*4+j];
      #pragma unroll
      for (int i=0;i<4;++i)
        #pragma unroll
        for (int j=0;j<4;++j) acc[i][j] += a[i]*bb[j];
    }
    __syncthreads();
  }
  // out_bh (B,N,DIM): row b*512+n, col h*64+dd
  #pragma unroll
  for (int i = 0; i < 4; ++i) {
    int n = rowBase + ty*4 + i;
    float* p = obh + ((size_t)(b*NN + n))*DIM + h*HD + tx*4;
    *(float4*)p = make_float4(acc[i][0], acc[i][1], acc[i][2], acc[i][3]);
  }
}

// ---------------- Kernel 5: proj GEMM + bias ----------------
__global__ __launch_bounds__(256) void proj_kernel(
    const float* __restrict__ obh, const float* __restrict__ pw,
    const float* __restrict__ pb, float* __restrict__ out)
{
  __shared__ float As[32][65];
  __shared__ float Bs[32][65];
  const int bx = blockIdx.x;   // 0..11 col tile
  const int by = blockIdx.y;   // 0..63 row tile
  const int t = threadIdx.x;
  const int ty = t >> 4, tx = t & 15;
  const float* A  = obh + (size_t)by * 64 * DIM;
  const float* Bw = pw  + (size_t)bx * 64 * DIM;
  float acc[4][4] = {};
  for (int kc = 0; kc < DIM; kc += 32) {
    #pragma unroll
    for (int i = 0; i < 2; ++i) {
      int f = t + 256 * i;
      int row = f >> 3, k4 = (f & 7) << 2;
      float4 av = *(const float4*)(A  + (size_t)row * DIM + kc + k4);
      float4 bv = *(const float4*)(Bw + (size_t)row * DIM + kc + k4);
      As[k4+0][row]=av.x; As[k4+1][row]=av.y; As[k4+2][row]=av.z; As[k4+3][row]=av.w;
      Bs[k4+0][row]=bv.x; Bs[k4+1][row]=bv.y; Bs[k4+2][row]=bv.z; Bs[k4+3][row]=bv.w;
    }
    __syncthreads();
    #pragma unroll
    for (int kk = 0; kk < 32; ++kk) {
      float a[4], bb[4];
      #pragma unroll
      for (int i=0;i<4;++i) a[i]=As[kk][ty*4+i];
      #pragma unroll
      for (int j=0;j<4;++j) bb[j]=Bs[kk][tx*4+j];
      #pragma unroll
      for (int i=0;i<4;++i)
        #pragma unroll
        for (int j=0;j<4;++j) acc[i][j] += a[i]*bb[j];
    }
    __syncthreads();
  }
  #pragma unroll
  for (int i = 0; i < 4; ++i) {
    int gm = by*64 + ty*4 + i;
    int gn = bx*64 + tx*4;
    float4 bias = *(const float4*)(pb + gn);
    float* p = out + (size_t)gm * DIM + gn;
    *(float4*)p = make_float4(acc[i][0]+bias.x, acc[i][1]+bias.y,
                              acc[i][2]+bias.z, acc[i][3]+bias.w);
  }
}

extern "C" void kernel_launch(void* const* d_in, const int* in_sizes, int n_in,
                              void* d_out, int out_size, void* d_ws, size_t ws_size,
                              hipStream_t stream) {
  const float* x      = (const float*)d_in[0];
  const float* qkv_w  = (const float*)d_in[1];
  const float* ln_w   = (const float*)d_in[2];
  const float* ln_b   = (const float*)d_in[3];
  const float* proj_w = (const float*)d_in[4];
  const float* proj_b = (const float*)d_in[5];
  float* out      = (float*)d_out;
  float* attn_out = out + OUT0_ELEMS;

  char* ws = (char*)d_ws;
  double* hsum = (double*)ws;                 // 16 doubles (sum, sumsq per batch)
  float* qws = (float*)(ws + 256);
  float* kws = qws + BHND;
  float* vws = kws + BHND;
  float* obh = qws;                           // alias: q2 dead after attn_kernel

  hipMemsetAsync(hsum, 0, 128, stream);
  qkv_kernel   <<<dim3(36, 64),        256, 0, stream>>>(x, qkv_w, qws, kws, vws);
  normsq_kernel<<<dim3(12288),         256, 0, stream>>>(qws, kws);
  attn_kernel  <<<dim3(64, HEADS, BB), 256, 0, stream>>>(qws, kws, attn_out, hsum);
  norm_pv_kernel<<<dim3(8, HEADS, BB), 256, 0, stream>>>(attn_out, vws, ln_w, ln_b, hsum, obh);
  proj_kernel  <<<dim3(12, 64),        256, 0, stream>>>(obh, proj_w, proj_b, out);
}

// Round 2
// 317.181 us; speedup vs baseline: 2.4089x; 2.4089x over previous
//
#include <hip/hip_runtime.h>

typedef __attribute__((ext_vector_type(8))) short bf16x8;
typedef __attribute__((ext_vector_type(4))) float f32x4;

#define HEADS 12
#define NN 512
#define BB 8
#define DIM 768
#define LDK 72    // BK=64 LDS row: 64 bf16 + 8 pad  (144B stride, 16B aligned, conflict-free)
#define LDK32 40  // BK=32 LDS row: 32 bf16 + 8 pad  (80B stride)
#define OUT0_ELEMS ((size_t)BB*NN*DIM)

__device__ __forceinline__ ushort f2bf(float f) {
  union { float f; uint u; } v; v.f = f;
  uint r = v.u + 0x7fffu + ((v.u >> 16) & 1u);   // RNE
  return (ushort)(r >> 16);
}

// ---------- convert fp32 weights -> bf16 (8 elems / thread) ----------
__global__ __launch_bounds__(256) void cvt_kernel(const float* __restrict__ in,
                                                  ushort* __restrict__ out, int n8) {
  int i = blockIdx.x * 256 + threadIdx.x;
  if (i >= n8) return;
  float4 a = ((const float4*)in)[i*2], b = ((const float4*)in)[i*2+1];
  uint4 o;
  o.x = f2bf(a.x) | ((uint)f2bf(a.y) << 16);
  o.y = f2bf(a.z) | ((uint)f2bf(a.w) << 16);
  o.z = f2bf(b.x) | ((uint)f2bf(b.y) << 16);
  o.w = f2bf(b.z) | ((uint)f2bf(b.w) << 16);
  ((uint4*)out)[i] = o;
}

// ---------- QKV GEMM (bf16 MFMA) + fused L2-normalize-square + V transpose ----------
// out q2b/k2b: bf16 [B,H,N,64] = q_d^2 / sum_d q_d^2 ; vt: bf16 [B,H,64,N]
__global__ __launch_bounds__(256) void qkv_gemm(
    const float* __restrict__ x, const ushort* __restrict__ wb,
    ushort* __restrict__ q2b, ushort* __restrict__ k2b, ushort* __restrict__ vt)
{
  __shared__ ushort As[128 * LDK];
  __shared__ ushort Bs[128 * LDK];
  const int t = threadIdx.x, l = t & 63, w = t >> 6;
  const int bx = blockIdx.x, by = blockIdx.y;     // col tile (18), row tile (32)
  const int rowbase = by * 128, colbase = bx * 128;
  const int wr = w >> 1, wc = w & 1, lr = l & 15, lg = l >> 4;
  f32x4 acc[4][4] = {};

  for (int kc = 0; kc < DIM; kc += 64) {
    #pragma unroll
    for (int i = 0; i < 4; ++i) {
      int c = t + 256 * i;
      int r = c >> 3, k16 = c & 7;                // 16B chunk (8 bf16) per row of 64
      // A: x fp32 -> bf16
      const float* src = x + (size_t)(rowbase + r) * DIM + kc + k16 * 8;
      float4 v0 = *(const float4*)src, v1 = *(const float4*)(src + 4);
      uint4 pk;
      pk.x = f2bf(v0.x) | ((uint)f2bf(v0.y) << 16);
      pk.y = f2bf(v0.z) | ((uint)f2bf(v0.w) << 16);
      pk.z = f2bf(v1.x) | ((uint)f2bf(v1.y) << 16);
      pk.w = f2bf(v1.z) | ((uint)f2bf(v1.w) << 16);
      *(uint4*)(As + r * LDK + k16 * 8) = pk;
      // B: wb bf16 direct
      *(uint4*)(Bs + r * LDK + k16 * 8) =
          *(const uint4*)(wb + (size_t)(colbase + r) * DIM + kc + k16 * 8);
    }
    __syncthreads();
    #pragma unroll
    for (int ks = 0; ks < 2; ++ks) {
      bf16x8 af[4], bg[4];
      #pragma unroll
      for (int i = 0; i < 4; ++i)
        af[i] = *(const bf16x8*)(As + (wr*64 + i*16 + lr) * LDK + ks*32 + lg*8);
      #pragma unroll
      for (int j = 0; j < 4; ++j)
        bg[j] = *(const bf16x8*)(Bs + (wc*64 + j*16 + lr) * LDK + ks*32 + lg*8);
      #pragma unroll
      for (int i = 0; i < 4; ++i)
        #pragma unroll
        for (int j = 0; j < 4; ++j)
          acc[i][j] = __builtin_amdgcn_mfma_f32_16x16x32_bf16(af[i], bg[j], acc[i][j], 0, 0, 0);
    }
    __syncthreads();
  }

  const int gcol = colbase + wc * 64;             // wave covers exactly one head (64 cols)
  const int sel = gcol / DIM;                     // 0=q 1=k 2=v
  const int h = (gcol % DIM) / 64;
  if (sel < 2) {
    ushort* dst = (sel == 0) ? q2b : k2b;
    #pragma unroll
    for (int i = 0; i < 4; ++i) {
      #pragma unroll
      for (int r = 0; r < 4; ++r) {
        float vj[4]; float s = 0.f;
        #pragma unroll
        for (int j = 0; j < 4; ++j) { vj[j] = acc[i][j][r]; s += vj[j] * vj[j]; }
        #pragma unroll
        for (int off = 1; off < 16; off <<= 1) s += __shfl_xor(s, off);
        float inv = 1.0f / s;                      // sum_d q_d^2 over the head
        int row = rowbase + wr*64 + i*16 + lg*4 + r;
        int b = row >> 9, n = row & 511;
        ushort* o = dst + (((size_t)(b * HEADS + h) * NN + n) << 6);
        #pragma unroll
        for (int j = 0; j < 4; ++j) o[j*16 + lr] = f2bf(vj[j] * vj[j] * inv);
      }
    }
  } else {
    #pragma unroll
    for (int i = 0; i < 4; ++i) {
      int row0 = rowbase + wr*64 + i*16 + lg*4;
      int b = row0 >> 9, n0 = row0 & 511;
      #pragma unroll
      for (int j = 0; j < 4; ++j) {
        int d = j*16 + lr;
        ushort4 pk;
        pk.x = f2bf(acc[i][j][0]); pk.y = f2bf(acc[i][j][1]);
        pk.z = f2bf(acc[i][j][2]); pk.w = f2bf(acc[i][j][3]);
        *(ushort4*)(vt + (((size_t)(b * HEADS + h) * 64 + d) << 9) + n0) = pk;
      }
    }
  }
}

// ---------- attn = q2 @ k2^T (bf16 MFMA), raw fp32 -> d_out, + LN stats ----------
__global__ __launch_bounds__(256) void attn_gemm(
    const ushort* __restrict__ q2b, const ushort* __restrict__ k2b,
    float* __restrict__ attn, double* __restrict__ hsum)
{
  __shared__ ushort As[128 * LDK];
  __shared__ ushort Bs[128 * LDK];
  __shared__ float red[8];
  const int t = threadIdx.x, l = t & 63, w = t >> 6;
  const int tile = blockIdx.x, h = blockIdx.y, b = blockIdx.z;
  const int rowbase = (tile >> 2) * 128, colbase = (tile & 3) * 128;
  const size_t bh = (size_t)(b * HEADS + h);
  const ushort* Aq = q2b + (bh << 15) + ((size_t)rowbase << 6);
  const ushort* Bk = k2b + (bh << 15) + ((size_t)colbase << 6);
  #pragma unroll
  for (int i = 0; i < 4; ++i) {
    int c = t + 256 * i;
    int r = c >> 3, k16 = c & 7;
    *(uint4*)(As + r * LDK + k16 * 8) = *(const uint4*)(Aq + ((size_t)r << 6) + k16 * 8);
    *(uint4*)(Bs + r * LDK + k16 * 8) = *(const uint4*)(Bk + ((size_t)r << 6) + k16 * 8);
  }
  __syncthreads();
  const int wr = w >> 1, wc = w & 1, lr = l & 15, lg = l >> 4;
  f32x4 acc[4][4] = {};
  #pragma unroll
  for (int ks = 0; ks < 2; ++ks) {
    bf16x8 af[4], bg[4];
    #pragma unroll
    for (int i = 0; i < 4; ++i)
      af[i] = *(const bf16x8*)(As + (wr*64 + i*16 + lr) * LDK + ks*32 + lg*8);
    #pragma unroll
    for (int j = 0; j < 4; ++j)
      bg[j] = *(const bf16x8*)(Bs + (wc*64 + j*16 + lr) * LDK + ks*32 + lg*8);
    #pragma unroll
    for (int i = 0; i < 4; ++i)
      #pragma unroll
      for (int j = 0; j < 4; ++j)
        acc[i][j] = __builtin_amdgcn_mfma_f32_16x16x32_bf16(af[i], bg[j], acc[i][j], 0, 0, 0);
  }
  float s1 = 0.f, s2 = 0.f;
  float* op = attn + ((bh << 9) + rowbase) * NN + colbase;
  #pragma unroll
  for (int i = 0; i < 4; ++i) {
    #pragma unroll
    for (int r = 0; r < 4; ++r) {
      int rr = wr*64 + i*16 + lg*4 + r;
      #pragma unroll
      for (int j = 0; j < 4; ++j) {
        float val = acc[i][j][r];
        s1 += val; s2 += val * val;
        op[(size_t)rr * NN + wc*64 + j*16 + lr] = val;
      }
    }
  }
  #pragma unroll
  for (int off = 1; off < 64; off <<= 1) { s1 += __shfl_xor(s1, off); s2 += __shfl_xor(s2, off); }
  if (l == 0) { red[w] = s1; red[4 + w] = s2; }
  __syncthreads();
  if (t == 0) {
    double d1 = (double)red[0] + red[1] + red[2] + red[3];
    double d2 = (double)red[4] + red[5] + red[6] + red[7];
    atomicAdd(&hsum[b * 2], d1);
    atomicAdd(&hsum[b * 2 + 1], d2);
  }
}

// ---------- LayerNorm in-place (output 1) + PV MFMA -> obh bf16 ----------
__global__ __launch_bounds__(256) void norm_pv(
    float* __restrict__ attn, const ushort* __restrict__ vt,
    const float* __restrict__ lnw, const float* __restrict__ lnb,
    const double* __restrict__ hsum, ushort* __restrict__ obh)
{
  __shared__ ushort As[128 * LDK32];
  __shared__ ushort Bs[64 * LDK32];
  const int t = threadIdx.x, l = t & 63, w = t >> 6;
  const int rt = blockIdx.x, h = blockIdx.y, b = blockIdx.z;
  const int rowbase = rt * 128;
  const size_t bh = (size_t)(b * HEADS + h);
  const double cnt = (double)HEADS * NN * NN;
  double mu = hsum[b * 2] / cnt;
  double var = hsum[b * 2 + 1] / cnt - mu * mu;
  const float mean = (float)mu;
  const float istd = (float)(1.0 / sqrt(var + 1e-5));
  float* arow = attn + ((bh << 9) + rowbase) * NN;
  const float* lwr = lnw + ((size_t)h * NN + rowbase) * NN;
  const float* lbr = lnb + ((size_t)h * NN + rowbase) * NN;
  const ushort* V = vt + (bh << 15);
  const int lr = l & 15, lg = l >> 4;
  f32x4 acc[2][4] = {};

  for (int kc = 0; kc < NN; kc += 32) {
    #pragma unroll
    for (int i = 0; i < 4; ++i) {
      int c = t + 256 * i;
      int r = c >> 3, q4 = c & 7;                  // 4 fp32 per chunk
      size_t g = (size_t)r * NN + kc + q4 * 4;
      float4 av = *(const float4*)(arow + g);
      float4 lw = *(const float4*)(lwr + g);
      float4 lb = *(const float4*)(lbr + g);
      float4 nv;
      nv.x = (av.x - mean) * istd * lw.x + lb.x;
      nv.y = (av.y - mean) * istd * lw.y + lb.y;
      nv.z = (av.z - mean) * istd * lw.z + lb.z;
      nv.w = (av.w - mean) * istd * lw.w + lb.w;
      *(float4*)(arow + g) = nv;                   // final attn output (in place)
      uint2 pk;
      pk.x = f2bf(nv.x) | ((uint)f2bf(nv.y) << 16);
      pk.y = f2bf(nv.z) | ((uint)f2bf(nv.w) << 16);
      *(uint2*)(As + r * LDK32 + q4 * 4) = pk;
    }
    {
      int r = t >> 2, k16 = t & 3;                 // Vt tile 64 x 32
      *(uint4*)(Bs + r * LDK32 + k16 * 8) =
          *(const uint4*)(V + ((size_t)r << 9) + kc + k16 * 8);
    }
    __syncthreads();
    bf16x8 af[2], bg[4];
    #pragma unroll
    for (int i = 0; i < 2; ++i)
      af[i] = *(const bf16x8*)(As + (w*32 + i*16 + lr) * LDK32 + lg*8);
    #pragma unroll
    for (int j = 0; j < 4; ++j)
      bg[j] = *(const bf16x8*)(Bs + (j*16 + lr) * LDK32 + lg*8);
    #pragma unroll
    for (int i = 0; i < 2; ++i)
      #pragma unroll
      for (int j = 0; j < 4; ++j)
        acc[i][j] = __builtin_amdgcn_mfma_f32_16x16x32_bf16(af[i], bg[j], acc[i][j], 0, 0, 0);
    __syncthreads();
  }
  #pragma unroll
  for (int i = 0; i < 2; ++i) {
    int gr = b * NN + rowbase + w*32 + i*16 + lg*4;
    #pragma unroll
    for (int j = 0; j < 4; ++j) {
      int gc = h * 64 + j*16 + lr;
      #pragma unroll
      for (int r = 0; r < 4; ++r)
        obh[(size_t)(gr + r) * DIM + gc] = f2bf(acc[i][j][r]);
    }
  }
}

// ---------- proj GEMM (bf16 MFMA) + bias -> fp32 out ----------
__global__ __launch_bounds__(256) void proj_gemm(
    const ushort* __restrict__ obh, const ushort* __restrict__ pwb,
    const float* __restrict__ pb, float* __restrict__ out)
{
  __shared__ ushort As[128 * LDK];
  __shared__ ushort Bs[128 * LDK];
  const int t = threadIdx.x, l = t & 63, w = t >> 6;
  const int bx = blockIdx.x, by = blockIdx.y;     // col tile (6), row tile (32)
  const int rowbase = by * 128, colbase = bx * 128;
  const int wr = w >> 1, wc = w & 1, lr = l & 15, lg = l >> 4;
  f32x4 acc[4][4] = {};
  for (int kc = 0; kc < DIM; kc += 64) {
    #pragma unroll
    for (int i = 0; i < 4; ++i) {
      int c = t + 256 * i;
      int r = c >> 3, k16 = c & 7;
      *(uint4*)(As + r * LDK + k16 * 8) =
          *(const uint4*)(obh + (size_t)(rowbase + r) * DIM + kc + k16 * 8);
      *(uint4*)(Bs + r * LDK + k16 * 8) =
          *(const uint4*)(pwb + (size_t)(colbase + r) * DIM + kc + k16 * 8);
    }
    __syncthreads();
    #pragma unroll
    for (int ks = 0; ks < 2; ++ks) {
      bf16x8 af[4], bg[4];
      #pragma unroll
      for (int i = 0; i < 4; ++i)
        af[i] = *(const bf16x8*)(As + (wr*64 + i*16 + lr) * LDK + ks*32 + lg*8);
      #pragma unroll
      for (int j = 0; j < 4; ++j)
        bg[j] = *(const bf16x8*)(Bs + (wc*64 + j*16 + lr) * LDK + ks*32 + lg*8);
      #pragma unroll
      for (int i = 0; i < 4; ++i)
        #pragma unroll
        for (int j = 0; j < 4; ++j)
          acc[i][j] = __builtin_amdgcn_mfma_f32_16x16x32_bf16(af[i], bg[j], acc[i][j], 0, 0, 0);
    }
    __syncthreads();
  }
  #pragma unroll
  for (int i = 0; i < 4; ++i) {
    #pragma unroll
    for (int r = 0; r < 4; ++r) {
      int row = rowbase + wr*64 + i*16 + lg*4 + r;
      #pragma unroll
      for (int j = 0; j < 4; ++j) {
        int col = colbase + wc*64 + j*16 + lr;
        out[(size_t)row * DIM + col] = acc[i][j][r] + pb[col];
      }
    }
  }
}

extern "C" void kernel_launch(void* const* d_in, const int* in_sizes, int n_in,
                              void* d_out, int out_size, void* d_ws, size_t ws_size,
                              hipStream_t stream) {
  const float* x      = (const float*)d_in[0];
  const float* qkv_w  = (const float*)d_in[1];
  const float* ln_w   = (const float*)d_in[2];
  const float* ln_b   = (const float*)d_in[3];
  const float* proj_w = (const float*)d_in[4];
  const float* proj_b = (const float*)d_in[5];
  float* out      = (float*)d_out;
  float* attn_out = out + OUT0_ELEMS;

  char* ws = (char*)d_ws;
  double* hsum = (double*)ws;                                 // 256 B
  ushort* wb   = (ushort*)(ws + 256);                         // 2304*768
  ushort* pwb  = wb + (size_t)2304 * 768;                     // 768*768
  ushort* q2b  = pwb + (size_t)768 * 768;                     // B*H*N*64
  ushort* k2b  = q2b + ((size_t)BB * HEADS * NN << 6);
  ushort* vt   = k2b + ((size_t)BB * HEADS * NN << 6);
  ushort* obh  = vt  + ((size_t)BB * HEADS * NN << 6);        // 4096*768

  hipMemsetAsync(hsum, 0, 256, stream);
  cvt_kernel<<<dim3(864), 256, 0, stream>>>(qkv_w, wb, 221184);
  cvt_kernel<<<dim3(288), 256, 0, stream>>>(proj_w, pwb, 73728);
  qkv_gemm  <<<dim3(18, 32),     256, 0, stream>>>(x, wb, q2b, k2b, vt);
  attn_gemm <<<dim3(16, HEADS, BB), 256, 0, stream>>>(q2b, k2b, attn_out, hsum);
  norm_pv   <<<dim3(4, HEADS, BB),  256, 0, stream>>>(attn_out, vt, ln_w, ln_b, hsum, obh);
  proj_gemm <<<dim3(6, 32),      256, 0, stream>>>(obh, pwb, proj_b, out);
}

// Round 3
// 259.902 us; speedup vs baseline: 2.9398x; 1.2204x over previous
//
#include <hip/hip_runtime.h>

typedef __attribute__((ext_vector_type(8))) short bf16x8;
typedef __attribute__((ext_vector_type(4))) float f32x4;

#define HEADS 12
#define NN 512
#define BB 8
#define DIM 768
#define LDK 72    // BK=64 LDS row: 64 bf16 + 8 pad  (144B stride; lr vs lr+8 2-way = free)
#define LDV 136   // 128 bf16 + 8 pad (272B stride)
#define OUT0_ELEMS ((size_t)BB*NN*DIM)

__device__ __forceinline__ ushort f2bf(float f) {
  union { float f; uint u; } v; v.f = f;
  uint r = v.u + 0x7fffu + ((v.u >> 16) & 1u);   // RNE
  return (ushort)(r >> 16);
}

// ---------- convert fp32 -> bf16, 8 elems / thread ----------
__global__ __launch_bounds__(256) void cvt_kernel(const float* __restrict__ in,
                                                  ushort* __restrict__ out, int n8) {
  int i = blockIdx.x * 256 + threadIdx.x;
  if (i >= n8) return;
  float4 a = ((const float4*)in)[i*2], b = ((const float4*)in)[i*2+1];
  uint4 o;
  o.x = f2bf(a.x) | ((uint)f2bf(a.y) << 16);
  o.y = f2bf(a.z) | ((uint)f2bf(a.w) << 16);
  o.z = f2bf(b.x) | ((uint)f2bf(b.y) << 16);
  o.w = f2bf(b.z) | ((uint)f2bf(b.w) << 16);
  ((uint4*)out)[i] = o;
}

// ---------- QKV GEMM (bf16 MFMA) + fused L2-normalize-square + V transpose ----------
__global__ __launch_bounds__(256) void qkv_gemm(
    const ushort* __restrict__ xb, const ushort* __restrict__ wb,
    ushort* __restrict__ q2b, ushort* __restrict__ k2b, ushort* __restrict__ vt)
{
  __shared__ ushort As[128 * LDK];
  __shared__ ushort Bs[128 * LDK];
  const int t = threadIdx.x, l = t & 63, w = t >> 6;
  const int bx = blockIdx.x, by = blockIdx.y;     // col tile (18), row tile (32)
  const int rowbase = by * 128, colbase = bx * 128;
  const int wr = w >> 1, wc = w & 1, lr = l & 15, lg = l >> 4;
  f32x4 acc[4][4] = {};

  for (int kc = 0; kc < DIM; kc += 64) {
    #pragma unroll
    for (int i = 0; i < 4; ++i) {
      int c = t + 256 * i;
      int r = c >> 3, k16 = c & 7;
      *(uint4*)(As + r * LDK + k16 * 8) =
          *(const uint4*)(xb + (size_t)(rowbase + r) * DIM + kc + k16 * 8);
      *(uint4*)(Bs + r * LDK + k16 * 8) =
          *(const uint4*)(wb + (size_t)(colbase + r) * DIM + kc + k16 * 8);
    }
    __syncthreads();
    #pragma unroll
    for (int ks = 0; ks < 2; ++ks) {
      bf16x8 af[4], bg[4];
      #pragma unroll
      for (int i = 0; i < 4; ++i)
        af[i] = *(const bf16x8*)(As + (wr*64 + i*16 + lr) * LDK + ks*32 + lg*8);
      #pragma unroll
      for (int j = 0; j < 4; ++j)
        bg[j] = *(const bf16x8*)(Bs + (wc*64 + j*16 + lr) * LDK + ks*32 + lg*8);
      #pragma unroll
      for (int i = 0; i < 4; ++i)
        #pragma unroll
        for (int j = 0; j < 4; ++j)
          acc[i][j] = __builtin_amdgcn_mfma_f32_16x16x32_bf16(af[i], bg[j], acc[i][j], 0, 0, 0);
    }
    __syncthreads();
  }

  const int gcol = colbase + wc * 64;             // wave = exactly one head (64 cols)
  const int sel = gcol / DIM;                     // 0=q 1=k 2=v
  const int h = (gcol % DIM) / 64;
  if (sel < 2) {
    ushort* dst = (sel == 0) ? q2b : k2b;
    #pragma unroll
    for (int i = 0; i < 4; ++i) {
      #pragma unroll
      for (int r = 0; r < 4; ++r) {
        float vj[4]; float s = 0.f;
        #pragma unroll
        for (int j = 0; j < 4; ++j) { vj[j] = acc[i][j][r]; s += vj[j] * vj[j]; }
        #pragma unroll
        for (int off = 1; off < 16; off <<= 1) s += __shfl_xor(s, off);
        float inv = 1.0f / s;
        int row = rowbase + wr*64 + i*16 + lg*4 + r;
        int b = row >> 9, n = row & 511;
        ushort* o = dst + (((size_t)(b * HEADS + h) * NN + n) << 6);
        #pragma unroll
        for (int j = 0; j < 4; ++j) o[j*16 + lr] = f2bf(vj[j] * vj[j] * inv);
      }
    }
  } else {
    #pragma unroll
    for (int i = 0; i < 4; ++i) {
      int row0 = rowbase + wr*64 + i*16 + lg*4;
      int b = row0 >> 9, n0 = row0 & 511;
      #pragma unroll
      for (int j = 0; j < 4; ++j) {
        int d = j*16 + lr;
        ushort4 pk;
        pk.x = f2bf(acc[i][j][0]); pk.y = f2bf(acc[i][j][1]);
        pk.z = f2bf(acc[i][j][2]); pk.w = f2bf(acc[i][j][3]);
        *(ushort4*)(vt + (((size_t)(b * HEADS + h) * 64 + d) << 9) + n0) = pk;
      }
    }
  }
}

// ---------- LN stats: recompute attn tiles via MFMA, accumulate sum/sumsq only ----------
__global__ __launch_bounds__(256) void stats_kernel(
    const ushort* __restrict__ q2b, const ushort* __restrict__ k2b,
    double* __restrict__ hsum)
{
  __shared__ ushort Qs[256 * LDK];
  __shared__ ushort Ks[128 * LDK];
  __shared__ float red[8];
  const int t = threadIdx.x, l = t & 63, w = t >> 6;
  const int rt = blockIdx.x, h = blockIdx.y, b = blockIdx.z;
  const size_t bh = (size_t)(b * HEADS + h);
  const int rowbase = rt * 256;
  const int lr = l & 15, lg = l >> 4;
  #pragma unroll
  for (int i = 0; i < 8; ++i) {
    int c = t + 256 * i;
    int r = c >> 3, k16 = c & 7;
    *(uint4*)(Qs + r * LDK + k16 * 8) =
        *(const uint4*)(q2b + (bh << 15) + ((size_t)(rowbase + r) << 6) + k16 * 8);
  }
  float s1 = 0.f, s2 = 0.f;
  for (int ct = 0; ct < 4; ++ct) {
    #pragma unroll
    for (int i = 0; i < 4; ++i) {
      int c = t + 256 * i;
      int r = c >> 3, k16 = c & 7;
      *(uint4*)(Ks + r * LDK + k16 * 8) =
          *(const uint4*)(k2b + (bh << 15) + ((size_t)(ct*128 + r) << 6) + k16 * 8);
    }
    __syncthreads();
    bf16x8 af[4][2];
    #pragma unroll
    for (int i = 0; i < 4; ++i)
      #pragma unroll
      for (int ks = 0; ks < 2; ++ks)
        af[i][ks] = *(const bf16x8*)(Qs + (w*64 + i*16 + lr) * LDK + ks*32 + lg*8);
    #pragma unroll
    for (int j = 0; j < 8; ++j) {
      bf16x8 b0 = *(const bf16x8*)(Ks + (j*16 + lr) * LDK + lg*8);
      bf16x8 b1 = *(const bf16x8*)(Ks + (j*16 + lr) * LDK + 32 + lg*8);
      #pragma unroll
      for (int i = 0; i < 4; ++i) {
        f32x4 a = {};
        a = __builtin_amdgcn_mfma_f32_16x16x32_bf16(af[i][0], b0, a, 0, 0, 0);
        a = __builtin_amdgcn_mfma_f32_16x16x32_bf16(af[i][1], b1, a, 0, 0, 0);
        #pragma unroll
        for (int r = 0; r < 4; ++r) { s1 += a[r]; s2 += a[r]*a[r]; }
      }
    }
    __syncthreads();
  }
  #pragma unroll
  for (int off = 1; off < 64; off <<= 1) { s1 += __shfl_xor(s1, off); s2 += __shfl_xor(s2, off); }
  if (l == 0) { red[w] = s1; red[4 + w] = s2; }
  __syncthreads();
  if (t == 0) {
    double d1 = (double)red[0] + red[1] + red[2] + red[3];
    double d2 = (double)red[4] + red[5] + red[6] + red[7];
    atomicAdd(&hsum[b * 2], d1);
    atomicAdd(&hsum[b * 2 + 1], d2);
  }
}

// ---------- recompute attn strip, LN, write attn (final), PV -> obh ----------
__global__ __launch_bounds__(256) void norm_pv(
    const ushort* __restrict__ q2b, const ushort* __restrict__ k2b,
    const ushort* __restrict__ vt,
    const float* __restrict__ lnw, const float* __restrict__ lnb,
    const double* __restrict__ hsum,
    float* __restrict__ attn, ushort* __restrict__ obh)
{
  __shared__ ushort Qs[64 * LDK];    // 9.2 KB  (persistent Q2 tile, 64 rows)
  __shared__ ushort Ks[128 * LDK];   // 18.4 KB (streamed K2 col-tile)
  __shared__ ushort Vs[64 * LDV];    // 17.4 KB (streamed Vt tile: 64 d x 128 m)
  __shared__ ushort Ps[64 * LDV];    // 17.4 KB (normalized attn bf16, k-major over m)
  const int t = threadIdx.x, l = t & 63, w = t >> 6;
  const int rt = blockIdx.x, h = blockIdx.y, b = blockIdx.z;
  const size_t bh = (size_t)(b * HEADS + h);
  const int rowbase = rt * 64;
  const int lr = l & 15, lg = l >> 4;
  const double cnt = (double)HEADS * NN * NN;
  double mu = hsum[b * 2] / cnt;
  double var = hsum[b * 2 + 1] / cnt - mu * mu;
  const float mean = (float)mu;
  const float istd = (float)(1.0 / sqrt(var + 1e-5));

  #pragma unroll
  for (int i = 0; i < 2; ++i) {
    int c = t + 256 * i;
    int r = c >> 3, k16 = c & 7;
    *(uint4*)(Qs + r * LDK + k16 * 8) =
        *(const uint4*)(q2b + (bh << 15) + ((size_t)(rowbase + r) << 6) + k16 * 8);
  }
  f32x4 opv[4] = {};

  for (int ct = 0; ct < 4; ++ct) {
    #pragma unroll
    for (int i = 0; i < 4; ++i) {
      int c = t + 256 * i;
      int r = c >> 3, k16 = c & 7;
      *(uint4*)(Ks + r * LDK + k16 * 8) =
          *(const uint4*)(k2b + (bh << 15) + ((size_t)(ct*128 + r) << 6) + k16 * 8);
    }
    #pragma unroll
    for (int i = 0; i < 4; ++i) {
      int c = t + 256 * i;
      int r = c >> 4, k16 = c & 15;
      *(uint4*)(Vs + r * LDV + k16 * 8) =
          *(const uint4*)(vt + (bh << 15) + ((size_t)r << 9) + ct*128 + k16 * 8);
    }
    __syncthreads();
    // S = Q2_tile @ K2_tile^T : 64 x 128, wave w owns cols w*32..w*32+31
    #pragma unroll
    for (int i = 0; i < 4; ++i) {
      bf16x8 a0 = *(const bf16x8*)(Qs + (i*16 + lr) * LDK + lg*8);
      bf16x8 a1 = *(const bf16x8*)(Qs + (i*16 + lr) * LDK + 32 + lg*8);
      #pragma unroll
      for (int j = 0; j < 2; ++j) {
        bf16x8 b0 = *(const bf16x8*)(Ks + (w*32 + j*16 + lr) * LDK + lg*8);
        bf16x8 b1 = *(const bf16x8*)(Ks + (w*32 + j*16 + lr) * LDK + 32 + lg*8);
        f32x4 a = {};
        a = __builtin_amdgcn_mfma_f32_16x16x32_bf16(a0, b0, a, 0, 0, 0);
        a = __builtin_amdgcn_mfma_f32_16x16x32_bf16(a1, b1, a, 0, 0, 0);
        const int nl = i*16 + lg*4;            // local row base
        const int ml = w*32 + j*16 + lr;       // local col
        const int n = rowbase + nl;            // row within 512
        const int m = ct*128 + ml;             // col within 512
        const float* lwp = lnw + ((size_t)h * NN + n) * NN + m;
        const float* lbp = lnb + ((size_t)h * NN + n) * NN + m;
        float* ap = attn + ((bh << 9) + n) * NN + m;
        #pragma unroll
        for (int r = 0; r < 4; ++r) {
          float v = (a[r] - mean) * istd * lwp[(size_t)r * NN] + lbp[(size_t)r * NN];
          __builtin_nontemporal_store(v, ap + (size_t)r * NN);
          Ps[(nl + r) * LDV + ml] = f2bf(v);
        }
      }
    }
    __syncthreads();
    // PV: out[n][d] += sum_m P[n][m] * Vt[d][m]; wave w owns rows w*16..w*16+15
    #pragma unroll
    for (int ks = 0; ks < 4; ++ks) {
      bf16x8 ap = *(const bf16x8*)(Ps + (w*16 + lr) * LDV + ks*32 + lg*8);
      #pragma unroll
      for (int j = 0; j < 4; ++j) {
        bf16x8 bv = *(const bf16x8*)(Vs + (j*16 + lr) * LDV + ks*32 + lg*8);
        opv[j] = __builtin_amdgcn_mfma_f32_16x16x32_bf16(ap, bv, opv[j], 0, 0, 0);
      }
    }
    __syncthreads();
  }
  #pragma unroll
  for (int j = 0; j < 4; ++j) {
    int gc = h * 64 + j*16 + lr;
    #pragma unroll
    for (int r = 0; r < 4; ++r) {
      int gr = b * NN + rowbase + w*16 + lg*4 + r;
      obh[(size_t)gr * DIM + gc] = f2bf(opv[j][r]);
    }
  }
}

// ---------- proj GEMM (bf16 MFMA) + bias -> fp32 out ----------
__global__ __launch_bounds__(256) void proj_gemm(
    const ushort* __restrict__ obh, const ushort* __restrict__ pwb,
    const float* __restrict__ pb, float* __restrict__ out)
{
  __shared__ ushort As[128 * LDK];
  __shared__ ushort Bs[128 * LDK];
  const int t = threadIdx.x, l = t & 63, w = t >> 6;
  const int bx = blockIdx.x, by = blockIdx.y;
  const int rowbase = by * 128, colbase = bx * 128;
  const int wr = w >> 1, wc = w & 1, lr = l & 15, lg = l >> 4;
  f32x4 acc[4][4] = {};
  for (int kc = 0; kc < DIM; kc += 64) {
    #pragma unroll
    for (int i = 0; i < 4; ++i) {
      int c = t + 256 * i;
      int r = c >> 3, k16 = c & 7;
      *(uint4*)(As + r * LDK + k16 * 8) =
          *(const uint4*)(obh + (size_t)(rowbase + r) * DIM + kc + k16 * 8);
      *(uint4*)(Bs + r * LDK + k16 * 8) =
          *(const uint4*)(pwb + (size_t)(colbase + r) * DIM + kc + k16 * 8);
    }
    __syncthreads();
    #pragma unroll
    for (int ks = 0; ks < 2; ++ks) {
      bf16x8 af[4], bg[4];
      #pragma unroll
      for (int i = 0; i < 4; ++i)
        af[i] = *(const bf16x8*)(As + (wr*64 + i*16 + lr) * LDK + ks*32 + lg*8);
      #pragma unroll
      for (int j = 0; j < 4; ++j)
        bg[j] = *(const bf16x8*)(Bs + (wc*64 + j*16 + lr) * LDK + ks*32 + lg*8);
      #pragma unroll
      for (int i = 0; i < 4; ++i)
        #pragma unroll
        for (int j = 0; j < 4; ++j)
          acc[i][j] = __builtin_amdgcn_mfma_f32_16x16x32_bf16(af[i], bg[j], acc[i][j], 0, 0, 0);
    }
    __syncthreads();
  }
  #pragma unroll
  for (int i = 0; i < 4; ++i) {
    #pragma unroll
    for (int r = 0; r < 4; ++r) {
      int row = rowbase + wr*64 + i*16 + lg*4 + r;
      #pragma unroll
      for (int j = 0; j < 4; ++j) {
        int col = colbase + wc*64 + j*16 + lr;
        out[(size_t)row * DIM + col] = acc[i][j][r] + pb[col];
      }
    }
  }
}

extern "C" void kernel_launch(void* const* d_in, const int* in_sizes, int n_in,
                              void* d_out, int out_size, void* d_ws, size_t ws_size,
                              hipStream_t stream) {
  const float* x      = (const float*)d_in[0];
  const float* qkv_w  = (const float*)d_in[1];
  const float* ln_w   = (const float*)d_in[2];
  const float* ln_b   = (const float*)d_in[3];
  const float* proj_w = (const float*)d_in[4];
  const float* proj_b = (const float*)d_in[5];
  float* out      = (float*)d_out;
  float* attn_out = out + OUT0_ELEMS;

  char* ws = (char*)d_ws;
  double* hsum = (double*)ws;                                 // 128 B used
  ushort* wb   = (ushort*)(ws + 256);                         // 2304*768
  ushort* pwb  = wb  + (size_t)2304 * 768;                    // 768*768
  ushort* xb   = pwb + (size_t)768 * 768;                     // 4096*768
  ushort* q2b  = xb  + (size_t)4096 * 768;                    // B*H*N*64
  ushort* k2b  = q2b + ((size_t)BB * HEADS * NN << 6);
  ushort* vt   = k2b + ((size_t)BB * HEADS * NN << 6);
  ushort* obh  = vt  + ((size_t)BB * HEADS * NN << 6);        // 4096*768

  hipMemsetAsync(hsum, 0, 128, stream);
  cvt_kernel<<<dim3(864),  256, 0, stream>>>(qkv_w,  wb,  221184);
  cvt_kernel<<<dim3(288),  256, 0, stream>>>(proj_w, pwb, 73728);
  cvt_kernel<<<dim3(1536), 256, 0, stream>>>(x,      xb,  393216);
  qkv_gemm    <<<dim3(18, 32),        256, 0, stream>>>(xb, wb, q2b, k2b, vt);
  stats_kernel<<<dim3(2, HEADS, BB),  256, 0, stream>>>(q2b, k2b, hsum);
  norm_pv     <<<dim3(8, HEADS, BB),  256, 0, stream>>>(q2b, k2b, vt, ln_w, ln_b, hsum,
                                                        attn_out, obh);
  proj_gemm   <<<dim3(6, 32),         256, 0, stream>>>(obh, pwb, proj_b, out);
}